// Round 4
// baseline (760.652 us; speedup 1.0000x reference)
//
#include <hip/hip_runtime.h>
#include <hip/hip_bf16.h>

// Problem constants (from reference)
#define NNODES 1000000
#define INDIM  128
#define HIDC   256
#define BSZ    4096
#define N2C    12288     // 3*B
#define FANC   10
#define N1C    122880    // N2*FAN
#define N0C    1228800   // N1*FAN

typedef __bf16 bf16_t;
typedef bf16_t bf16x2 __attribute__((ext_vector_type(2)));
typedef bf16_t bf16x4 __attribute__((ext_vector_type(4)));
typedef bf16_t bf16x8 __attribute__((ext_vector_type(8)));
typedef float  f32x4  __attribute__((ext_vector_type(4)));

// ---------------------------------------------------------------------------
// All weight prep in ONE launch: fp32 [K][N] (optionally stacked SA;SB) ->
// bf16 [N][Ktot] so MFMA b-frags read 16B contiguous along K.
// ---------------------------------------------------------------------------
__global__ __launch_bounds__(256) void prep_all(const float* __restrict__ Ws0,
                                                const float* __restrict__ Wn0,
                                                const float* __restrict__ Ws1,
                                                const float* __restrict__ Wn1,
                                                const float* __restrict__ Wp1,
                                                const float* __restrict__ Wp2,
                                                bf16_t* __restrict__ Wt0,
                                                bf16_t* __restrict__ Wt1,
                                                bf16_t* __restrict__ WtP1,
                                                bf16_t* __restrict__ WtP2) {
  int t = blockIdx.x * 256 + threadIdx.x;
  if (t < 65536) {
    int n = t >> 8, k = t & 255;
    float v = (k < 128) ? Ws0[k * 256 + n] : Wn0[(k - 128) * 256 + n];
    Wt0[t] = (bf16_t)v;
  } else if (t < 196608) {
    int u = t - 65536; int n = u >> 9, k = u & 511;
    float v = (k < 256) ? Ws1[k * 256 + n] : Wn1[(k - 256) * 256 + n];
    Wt1[u] = (bf16_t)v;
  } else if (t < 262144) {
    int u = t - 196608; int n = u >> 8, k = u & 255;
    WtP1[u] = (bf16_t)Wp1[k * 256 + n];
  } else {
    int u = t - 262144; int n = u >> 8, k = u & 255;
    WtP2[u] = (bf16_t)Wp2[k * 256 + n];
  }
}

// ---------------------------------------------------------------------------
// FUSED layer-0: gather+mean-aggregate 64 dest rows into a padded LDS tile,
// then h[m0..m0+64) = relu(As @ [Ws0;Wn0] + b0) via MFMA reading A from LDS.
// Phase-1 gathers use PAIRED rows: float4/lane, lanes 0-31 cover one 512B row,
// lanes 32-63 a second row -> 1KB per VMEM instruction (halved issue count).
// ---------------------------------------------------------------------------
#define LDA0 264
__global__ __launch_bounds__(256) void fused0(const float* __restrict__ feat,
                                              const int* __restrict__ gids,
                                              const int* __restrict__ nidx,
                                              const bf16_t* __restrict__ Wt,
                                              const float* __restrict__ bias,
                                              bf16_t* __restrict__ h) {
  __shared__ __align__(16) bf16_t As[64 * LDA0];   // 33792 B
  __shared__ int nid_s[64 * FANC];
  __shared__ int self_s[64];
  int tid = threadIdx.x;
  int m0 = blockIdx.x * 64;

  // phase 0: stage node ids (coalesced nidx read, random 4B gids gather)
  for (int t = tid; t < 64 * FANC; t += 256)
    nid_s[t] = gids[nidx[(size_t)m0 * FANC + t]];
  if (tid < 64) self_s[tid] = gids[m0 + tid];
  __syncthreads();

  // phase 1: paired row gathers. wave handles dests [wv*16, wv*16+16), 2/iter.
  int wv = tid >> 6, lane = tid & 63;
  int half = lane >> 5, l31 = lane & 31;
  const float4* f4 = (const float4*)feat;
  for (int p = 0; p < 8; p++) {
    int d = wv * 16 + p * 2;            // pair (d, d+1)
    f32x4 accA = {0.f, 0.f, 0.f, 0.f};  // dest d   (even j lower, odd j upper)
    f32x4 accB = {0.f, 0.f, 0.f, 0.f};  // dest d+1
#pragma unroll
    for (int k = 0; k < 5; k++) {
      int ndA = nid_s[d * FANC + 2 * k + half];
      float4 vA = f4[(size_t)ndA * 32 + l31];
      accA.x += vA.x; accA.y += vA.y; accA.z += vA.z; accA.w += vA.w;
      int ndB = nid_s[(d + 1) * FANC + 2 * k + half];
      float4 vB = f4[(size_t)ndB * 32 + l31];
      accB.x += vB.x; accB.y += vB.y; accB.z += vB.z; accB.w += vB.w;
    }
    // combine halves: every lane ends with the full 10-neighbor sum for its cols
    accA.x += __shfl_xor(accA.x, 32); accA.y += __shfl_xor(accA.y, 32);
    accA.z += __shfl_xor(accA.z, 32); accA.w += __shfl_xor(accA.w, 32);
    accB.x += __shfl_xor(accB.x, 32); accB.y += __shfl_xor(accB.y, 32);
    accB.z += __shfl_xor(accB.z, 32); accB.w += __shfl_xor(accB.w, 32);
    // self rows, paired: lower half = dest d, upper half = dest d+1
    int sn = self_s[d + half];
    float4 xs = f4[(size_t)sn * 32 + l31];
    int dw = d + half;
    bf16_t* row = As + dw * LDA0;
    bf16x4 w0 = { (bf16_t)xs.x, (bf16_t)xs.y, (bf16_t)xs.z, (bf16_t)xs.w };
    *(bf16x4*)(row + l31 * 4) = w0;
    f32x4 ag = half ? accB : accA;
    bf16x4 w1 = { (bf16_t)(ag.x * 0.1f), (bf16_t)(ag.y * 0.1f),
                  (bf16_t)(ag.z * 0.1f), (bf16_t)(ag.w * 0.1f) };
    *(bf16x4*)(row + 128 + l31 * 4) = w1;
  }
  __syncthreads();

  // phase 2: MFMA. wave w owns cols [64w, 64w+64); 4 m-tiles of 16 rows.
  int l15 = lane & 15, quad = lane >> 4;
  int n0 = wv * 64;
  f32x4 acc[4][4] = {};
  for (int k0 = 0; k0 < 256; k0 += 32) {
    bf16x8 a[4], b[4];
#pragma unroll
    for (int mt = 0; mt < 4; mt++)
      a[mt] = *(const bf16x8*)(As + (mt * 16 + l15) * LDA0 + k0 + quad * 8);
#pragma unroll
    for (int nt = 0; nt < 4; nt++)
      b[nt] = *(const bf16x8*)(Wt + (size_t)(n0 + nt * 16 + l15) * 256 + k0 + quad * 8);
#pragma unroll
    for (int mt = 0; mt < 4; mt++)
#pragma unroll
      for (int nt = 0; nt < 4; nt++)
        acc[mt][nt] = __builtin_amdgcn_mfma_f32_16x16x32_bf16(a[mt], b[nt], acc[mt][nt], 0, 0, 0);
  }
#pragma unroll
  for (int mt = 0; mt < 4; mt++)
#pragma unroll
    for (int nt = 0; nt < 4; nt++) {
      int col = n0 + nt * 16 + l15;
      float bv = bias[col];
#pragma unroll
      for (int r = 0; r < 4; r++) {
        int row = m0 + mt * 16 + quad * 4 + r;
        float v = fmaxf(acc[mt][nt][r] + bv, 0.f);
        h[(size_t)row * 256 + col] = (bf16_t)v;
      }
    }
}

// ---------------------------------------------------------------------------
// FUSED layer-1: gather+aggregate 32 dest rows from bf16 h (L3-resident) into
// LDS, then h2[m0..m0+32) = As1 @ [Ws1;Wn1] + b1 (bf16 out, no relu). K=512.
// ---------------------------------------------------------------------------
#define LDA1 520
__global__ __launch_bounds__(256) void fused1(const bf16_t* __restrict__ h,
                                              const int* __restrict__ nidx,
                                              const bf16_t* __restrict__ Wt,
                                              const float* __restrict__ bias,
                                              bf16_t* __restrict__ h2) {
  __shared__ __align__(16) bf16_t As[32 * LDA1];   // 33280 B
  __shared__ int nid_s[32 * FANC];
  int tid = threadIdx.x;
  int m0 = blockIdx.x * 32;

  for (int t = tid; t < 32 * FANC; t += 256)
    nid_s[t] = nidx[(size_t)m0 * FANC + t];
  __syncthreads();

  int wv = tid >> 6, lane = tid & 63;
  const bf16x4* h4 = (const bf16x4*)h;
  for (int i = 0; i < 8; i++) {
    int d = wv * 8 + i;
    float a0 = 0.f, a1 = 0.f, a2 = 0.f, a3 = 0.f;
#pragma unroll
    for (int j = 0; j < FANC; j++) {
      int nd = nid_s[d * FANC + j];
      bf16x4 v = h4[(size_t)nd * 64 + lane];
      a0 += (float)v[0]; a1 += (float)v[1]; a2 += (float)v[2]; a3 += (float)v[3];
    }
    bf16x4 xs = h4[(size_t)(m0 + d) * 64 + lane];
    bf16_t* row = As + d * LDA1;
    *(bf16x4*)(row + lane * 4) = xs;
    bf16x4 ag = { (bf16_t)(a0 * 0.1f), (bf16_t)(a1 * 0.1f),
                  (bf16_t)(a2 * 0.1f), (bf16_t)(a3 * 0.1f) };
    *(bf16x4*)(row + 256 + lane * 4) = ag;
  }
  __syncthreads();

  int l15 = lane & 15, quad = lane >> 4;
  int n0 = wv * 64;
  f32x4 acc[2][4] = {};
  for (int k0 = 0; k0 < 512; k0 += 32) {
    bf16x8 a[2], b[4];
#pragma unroll
    for (int mt = 0; mt < 2; mt++)
      a[mt] = *(const bf16x8*)(As + (mt * 16 + l15) * LDA1 + k0 + quad * 8);
#pragma unroll
    for (int nt = 0; nt < 4; nt++)
      b[nt] = *(const bf16x8*)(Wt + (size_t)(n0 + nt * 16 + l15) * 512 + k0 + quad * 8);
#pragma unroll
    for (int mt = 0; mt < 2; mt++)
#pragma unroll
      for (int nt = 0; nt < 4; nt++)
        acc[mt][nt] = __builtin_amdgcn_mfma_f32_16x16x32_bf16(a[mt], b[nt], acc[mt][nt], 0, 0, 0);
  }
#pragma unroll
  for (int mt = 0; mt < 2; mt++)
#pragma unroll
    for (int nt = 0; nt < 4; nt++) {
      int col = n0 + nt * 16 + l15;
      float bv = bias[col];
#pragma unroll
      for (int r = 0; r < 4; r++) {
        int row = m0 + mt * 16 + quad * 4 + r;
        h2[(size_t)row * 256 + col] = (bf16_t)(acc[mt][nt][r] + bv);
      }
    }
}

// ---------------------------------------------------------------------------
// FUSED predictor: per block, 64 z-rows end-to-end (h2 is bf16 now).
// ---------------------------------------------------------------------------
#define LDP 264
__device__ __forceinline__ void gemm_tile_lds(const bf16_t* __restrict__ Asrc,
                                              const bf16_t* __restrict__ Wt,
                                              const float* __restrict__ bias,
                                              bf16_t* __restrict__ Dst,
                                              int wv, int lane) {
  int l15 = lane & 15, quad = lane >> 4;
  int n0 = wv * 64;
  f32x4 acc[4][4] = {};
  for (int k0 = 0; k0 < 256; k0 += 32) {
    bf16x8 a[4], b[4];
#pragma unroll
    for (int mt = 0; mt < 4; mt++)
      a[mt] = *(const bf16x8*)(Asrc + (mt * 16 + l15) * LDP + k0 + quad * 8);
#pragma unroll
    for (int nt = 0; nt < 4; nt++)
      b[nt] = *(const bf16x8*)(Wt + (size_t)(n0 + nt * 16 + l15) * 256 + k0 + quad * 8);
#pragma unroll
    for (int mt = 0; mt < 4; mt++)
#pragma unroll
      for (int nt = 0; nt < 4; nt++)
        acc[mt][nt] = __builtin_amdgcn_mfma_f32_16x16x32_bf16(a[mt], b[nt], acc[mt][nt], 0, 0, 0);
  }
#pragma unroll
  for (int mt = 0; mt < 4; mt++)
#pragma unroll
    for (int nt = 0; nt < 4; nt++) {
      int col = n0 + nt * 16 + l15;
      float bv = bias[col];
#pragma unroll
      for (int r = 0; r < 4; r++) {
        int row = mt * 16 + quad * 4 + r;
        Dst[row * LDP + col] = (bf16_t)fmaxf(acc[mt][nt][r] + bv, 0.f);
      }
    }
}

__global__ __launch_bounds__(256) void pred_fused(const bf16_t* __restrict__ h2,
                                                  const bf16_t* __restrict__ WtP1,
                                                  const float* __restrict__ bp1,
                                                  const bf16_t* __restrict__ WtP2,
                                                  const float* __restrict__ bp2,
                                                  const float* __restrict__ Wp3,
                                                  const float* __restrict__ bp3,
                                                  float* __restrict__ out) {
  __shared__ __align__(16) bf16_t Z0[64 * LDP];
  __shared__ __align__(16) bf16_t Z1[64 * LDP];
  int tid = threadIdx.x, wv = tid >> 6, lane = tid & 63;
  int m0 = blockIdx.x * 64;

  // phase A: build z tile (rows m0..m0+64)
  for (int i = 0; i < 16; i++) {
    int rl = wv * 16 + i;
    int r = m0 + rl;
    int a = r & 4095, b = r + 4096;
    bf16x4 va = *(const bf16x4*)(h2 + (size_t)a * 256 + lane * 4);
    bf16x4 vb = *(const bf16x4*)(h2 + (size_t)b * 256 + lane * 4);
    bf16x4 o = { (bf16_t)((float)va[0] * (float)vb[0]),
                 (bf16_t)((float)va[1] * (float)vb[1]),
                 (bf16_t)((float)va[2] * (float)vb[2]),
                 (bf16_t)((float)va[3] * (float)vb[3]) };
    *(bf16x4*)(Z0 + rl * LDP + lane * 4) = o;
  }
  __syncthreads();

  // phase B/C: two GEMMs, ping-pong
  gemm_tile_lds(Z0, WtP1, bp1, Z1, wv, lane);
  __syncthreads();
  gemm_tile_lds(Z1, WtP2, bp2, Z0, wv, lane);
  __syncthreads();

  // phase D: scores
  float4 w = *(const float4*)(Wp3 + lane * 4);
  float b3 = bp3[0];
  for (int i = 0; i < 16; i++) {
    int rl = wv * 16 + i;
    bf16x4 v = *(const bf16x4*)(Z0 + rl * LDP + lane * 4);
    float s = (float)v[0] * w.x + (float)v[1] * w.y + (float)v[2] * w.z + (float)v[3] * w.w;
    for (int off = 32; off > 0; off >>= 1) s += __shfl_down(s, off);
    if (lane == 0) out[m0 + rl] = s + b3;
  }
}

// ---------------------------------------------------------------------------
extern "C" void kernel_launch(void* const* d_in, const int* in_sizes, int n_in,
                              void* d_out, int out_size, void* d_ws, size_t ws_size,
                              hipStream_t stream) {
  const float* node_feat = (const float*)d_in[0];
  const int*   gids0     = (const int*)d_in[1];
  const int*   nidx0     = (const int*)d_in[2];
  const int*   nidx1     = (const int*)d_in[3];
  const float* Wself0    = (const float*)d_in[4];
  const float* Wneigh0   = (const float*)d_in[5];
  const float* b0        = (const float*)d_in[6];
  const float* Wself1    = (const float*)d_in[7];
  const float* Wneigh1   = (const float*)d_in[8];
  const float* b1        = (const float*)d_in[9];
  const float* Wp1       = (const float*)d_in[10];
  const float* bp1       = (const float*)d_in[11];
  const float* Wp2       = (const float*)d_in[12];
  const float* bp2       = (const float*)d_in[13];
  const float* Wp3       = (const float*)d_in[14];
  const float* bp3       = (const float*)d_in[15];

  char* ws = (char*)d_ws;
  bf16_t* Wt0  = (bf16_t*)(ws + 0);           // 256x256 bf16 = 128KB
  bf16_t* Wt1  = (bf16_t*)(ws + (128 << 10)); // 256x512 bf16 = 256KB
  bf16_t* WtP1 = (bf16_t*)(ws + (384 << 10));
  bf16_t* WtP2 = (bf16_t*)(ws + (512 << 10));
  char* big = ws + (1 << 20);
  bf16_t* h  = (bf16_t*)big;                       // 122880x256 bf16 = 60MB
  bf16_t* h2 = (bf16_t*)(big + (64ULL << 20));     // 12288x256 bf16 = 6MB
  float* out = (float*)d_out;

  // Single weight-prep launch
  prep_all<<<1280, 256, 0, stream>>>(Wself0, Wneigh0, Wself1, Wneigh1, Wp1, Wp2,
                                     Wt0, Wt1, WtP1, WtP2);

  // Layer 0 fused: h = relu([x|agg] @ [Ws0;Wn0] + b0)
  fused0<<<N1C / 64, 256, 0, stream>>>(node_feat, gids0, nidx0, Wt0, b0, h);

  // Layer 1 fused: h2 = [h|agg] @ [Ws1;Wn1] + b1
  fused1<<<N2C / 32, 256, 0, stream>>>(h, nidx1, Wt1, b1, h2);

  // Predictor fused: z -> P1 -> P2 -> P3 in one kernel
  pred_fused<<<8192 / 64, 256, 0, stream>>>(h2, WtP1, bp1, WtP2, bp2, Wp3, bp3, out);
}